// Round 12
// baseline (439.117 us; speedup 1.0000x reference)
//
#include <hip/hip_runtime.h>

#define N 8192
#define D 128

typedef __attribute__((ext_vector_type(8))) short bf16x8;
typedef __attribute__((ext_vector_type(4))) float f32x4;

__device__ __forceinline__ unsigned short f32_to_bf16_rne(float f) {
  unsigned int u = __float_as_uint(f);
  unsigned int r = (u + 0x7FFFu + ((u >> 16) & 1u)) >> 16;
  return (unsigned short)r;
}
__device__ __forceinline__ float bf16_to_f32(unsigned short h) {
  return __uint_as_float(((unsigned int)h) << 16);
}
__device__ __forceinline__ float fast_sqrt(float x) {
  float r;
  asm("v_sqrt_f32 %0, %1" : "=v"(r) : "v"(x));
  return r;
}
__device__ __forceinline__ void load_lds16(const void* g, void* l) {
  __builtin_amdgcn_global_load_lds((const __attribute__((address_space(1))) void*)g,
                                   (__attribute__((address_space(3))) void*)l,
                                   16, 0, 0);
}

// Kernel P: pack mask to bitplanes + per-row counts. One wave per row.
__global__ __launch_bounds__(256) void pack_kernel(
    const float* __restrict__ mask, unsigned long long* __restrict__ bp,
    float* __restrict__ cnt) {
  const int wv = threadIdx.x >> 6, lane = threadIdx.x & 63;
  const int row = blockIdx.x * 4 + wv;
  const f32x4* mrow = (const f32x4*)(mask + (size_t)row * N);
  int c = 0;
#pragma unroll 4
  for (int i = 0; i < 32; ++i) {
    f32x4 v = __builtin_nontemporal_load(&mrow[i * 64 + lane]);
    unsigned long long b0 = __ballot(v.x != 0.0f);
    unsigned long long b1 = __ballot(v.y != 0.0f);
    unsigned long long b2 = __ballot(v.z != 0.0f);
    unsigned long long b3 = __ballot(v.w != 0.0f);
    c += (v.x != 0.0f) + (v.y != 0.0f) + (v.z != 0.0f) + (v.w != 0.0f);
    if (lane == 0) {
      unsigned long long* d = bp + ((size_t)i * N + row) * 4;
      d[0] = b0; d[1] = b1; d[2] = b2; d[3] = b3;
    }
  }
#pragma unroll
  for (int off = 32; off; off >>= 1) c += __shfl_xor(c, off);
  if (lane == 0) cnt[row] = (float)c;
}

// Kernel A: L2-normalize pred/neg; emit phi/plo (bf16 hi/lo split), sq, nd.
__global__ __launch_bounds__(256) void norm_kernel(
    const float* __restrict__ pred, const float* __restrict__ neg,
    unsigned short* __restrict__ phi, unsigned short* __restrict__ plo,
    float* __restrict__ sq, float* __restrict__ nd) {
  int wv = threadIdx.x >> 6;
  int lane = threadIdx.x & 63;
  int row = blockIdx.x * 4 + wv;
  float2 x = ((const float2*)(pred + (size_t)row * D))[lane];
  float2 y = ((const float2*)(neg + (size_t)row * D))[lane];
  float sx = x.x * x.x + x.y * x.y;
  float sy = y.x * y.x + y.y * y.y;
#pragma unroll
  for (int off = 32; off; off >>= 1) {
    sx += __shfl_xor(sx, off);
    sy += __shfl_xor(sy, off);
  }
  float invx = 1.0f / fmaxf(sqrtf(sx), 1e-12f);
  float invy = 1.0f / fmaxf(sqrtf(sy), 1e-12f);
  float2 px = make_float2(x.x * invx, x.y * invx);
  float2 pn = make_float2(y.x * invy, y.y * invy);

  unsigned short h0 = f32_to_bf16_rne(px.x), h1 = f32_to_bf16_rne(px.y);
  unsigned short l0 = f32_to_bf16_rne(px.x - bf16_to_f32(h0));
  unsigned short l1 = f32_to_bf16_rne(px.y - bf16_to_f32(h1));
  ushort2 hv; hv.x = h0; hv.y = h1;
  ushort2 lv; lv.x = l0; lv.y = l1;
  ((ushort2*)(phi + (size_t)row * D))[lane] = hv;
  ((ushort2*)(plo + (size_t)row * D))[lane] = lv;

  float sp = px.x * px.x + px.y * px.y;
  float dx = px.x - pn.x, dy = px.y - pn.y;
  float sd = dx * dx + dy * dy;
#pragma unroll
  for (int off = 32; off; off >>= 1) {
    sp += __shfl_xor(sp, off);
    sd += __shfl_xor(sd, off);
  }
  if (lane == 0) {
    sq[row] = sp;
    nd[row] = sd > 0.0f ? sqrtf(sd) : 0.0f;
  }
}

// Kernel B: 128x128 tile; DOUBLE-BUFFERED LDS staging (global_load_lds w16,
// stage kc+1 before consuming kc, one counted-vmcnt drain + barrier per kc),
// 4 waves 2x2, mfma 16x16x32 bf16 hi/lo 3-way split, bitmask epilogue.
// bw/sqj loads hoisted above the k-loop (latency hides under MFMA).
__global__ __launch_bounds__(256, 2) void pair_kernel(
    const unsigned short* __restrict__ phi, const unsigned short* __restrict__ plo,
    const float* __restrict__ sq, const unsigned long long* __restrict__ bp,
    float* __restrict__ ppos) {
  __shared__ __align__(16) unsigned short aHi[2][4096], aLo[2][4096];
  __shared__ __align__(16) unsigned short bHi[2][4096], bLo[2][4096];
  __shared__ float cbuf[4][64];

  const int bid = blockIdx.x;
  // 2D XCD partition: XCD (bid&7) owns a 16x32 (ib,jb) region (bijective).
  const int xcd = bid & 7, idx = bid >> 3;
  const int ib = (xcd >> 1) * 16 + (idx & 15);
  const int jb = (xcd & 1) * 32 + (idx >> 4);
  const int i0 = ib * 128, j0 = jb * 128;

  const int t = threadIdx.x;
  const int wv = t >> 6, lane = t & 63;
  const int wi = wv >> 1, wj = wv & 1;
  const int lr = lane & 15, lk = lane >> 4;

  const int srow = t >> 2;   // staging row within 64-row pass
  const int sch = t & 3;     // 16B chunk within the 64B k-slice

  // hoisted epilogue loads: bit-words + sq values (consumed after k-loop)
  unsigned long long bw[4][4];
  const unsigned long long* bbase = bp + (size_t)(jb >> 1) * N * 4 + (lr & 3);
#pragma unroll
  for (int fi = 0; fi < 4; ++fi)
#pragma unroll
    for (int r = 0; r < 4; ++r)
      bw[fi][r] = bbase[(size_t)(i0 + wi * 64 + fi * 16 + lk * 4 + r) * 4];
  const int brow = j0 + wj * 64 + lr;
  float sqj[4];
#pragma unroll
  for (int fj = 0; fj < 4; ++fj) sqj[fj] = sq[brow + fj * 16];
  float sqi[4][4];
#pragma unroll
  for (int fi = 0; fi < 4; ++fi)
#pragma unroll
    for (int r = 0; r < 4; ++r) sqi[fi][r] = sq[i0 + wi * 64 + fi * 16 + lk * 4 + r];

  f32x4 acc[4][4];
#pragma unroll
  for (int a = 0; a < 4; ++a)
#pragma unroll
    for (int b = 0; b < 4; ++b) acc[a][b] = (f32x4){0.f, 0.f, 0.f, 0.f};

#define STAGE(S, KC) do { \
  _Pragma("unroll") for (int pass = 0; pass < 2; ++pass) { \
    const int row_ = pass * 64 + srow; \
    const size_t ga_ = (size_t)(i0 + row_) * D + (KC) * 32 + sch * 8; \
    const size_t gb_ = (size_t)(j0 + row_) * D + (KC) * 32 + sch * 8; \
    const int lo_ = row_ * 32 + sch * 8; \
    load_lds16(phi + ga_, &aHi[S][lo_]); \
    load_lds16(plo + ga_, &aLo[S][lo_]); \
    load_lds16(phi + gb_, &bHi[S][lo_]); \
    load_lds16(plo + gb_, &bLo[S][lo_]); \
  } \
} while (0)

  STAGE(0, 0);
  asm volatile("s_waitcnt vmcnt(0)" ::: "memory");
  __builtin_amdgcn_s_barrier();

#pragma unroll
  for (int kc = 0; kc < 4; ++kc) {
    const int cur = kc & 1;
    if (kc < 3) STAGE(kc & 1 ? 0 : 1, kc + 1);  // issue next chunk first

    bf16x8 ah[4], al[4], bh[4], bl[4];
#pragma unroll
    for (int f = 0; f < 4; ++f) {
      const int ar = (wi * 64 + f * 16 + lr) * 32 + lk * 8;
      const int br = (wj * 64 + f * 16 + lr) * 32 + lk * 8;
      ah[f] = *(const bf16x8*)(&aHi[cur][ar]);
      al[f] = *(const bf16x8*)(&aLo[cur][ar]);
      bh[f] = *(const bf16x8*)(&bHi[cur][br]);
      bl[f] = *(const bf16x8*)(&bLo[cur][br]);
    }
#pragma unroll
    for (int fi = 0; fi < 4; ++fi)
#pragma unroll
      for (int fj = 0; fj < 4; ++fj) {
        acc[fi][fj] = __builtin_amdgcn_mfma_f32_16x16x32_bf16(ah[fi], bh[fj], acc[fi][fj], 0, 0, 0);
        acc[fi][fj] = __builtin_amdgcn_mfma_f32_16x16x32_bf16(ah[fi], bl[fj], acc[fi][fj], 0, 0, 0);
        acc[fi][fj] = __builtin_amdgcn_mfma_f32_16x16x32_bf16(al[fi], bh[fj], acc[fi][fj], 0, 0, 0);
      }
    if (kc < 3) {
      asm volatile("s_waitcnt vmcnt(0)" ::: "memory");  // next chunk landed
      __builtin_amdgcn_s_barrier();                     // + cur fully consumed
    }
  }
#undef STAGE

  // col = jb*128 + wj*64 + fj*16 + lr -> (col>>2)&63 = (jb&1)*32+wj*16+fj*4+(lr>>2)
  const int sh0 = (jb & 1) * 32 + wj * 16 + (lr >> 2);

  float pp[4][4];
#pragma unroll
  for (int a = 0; a < 4; ++a)
#pragma unroll
    for (int r = 0; r < 4; ++r) pp[a][r] = 0.f;

#pragma unroll
  for (int fi = 0; fi < 4; ++fi) {
#pragma unroll
    for (int r = 0; r < 4; ++r) {
      const unsigned long long w = bw[fi][r];
#pragma unroll
      for (int fj = 0; fj < 4; ++fj) {
        float d2 = sqi[fi][r] + sqj[fj] - 2.0f * acc[fi][fj][r];
        float dist = fast_sqrt(fmaxf(d2, 0.0f));
        pp[fi][r] += ((w >> (sh0 + fj * 4)) & 1ULL) ? dist : 0.0f;
      }
    }
  }

#pragma unroll
  for (int fi = 0; fi < 4; ++fi)
#pragma unroll
    for (int r = 0; r < 4; ++r) {
#pragma unroll
      for (int off = 1; off < 16; off <<= 1)
        pp[fi][r] += __shfl_xor(pp[fi][r], off);
    }
  __builtin_amdgcn_s_barrier();   // safe reuse boundary before cbuf writes
  if (lr == 0) {
#pragma unroll
    for (int fi = 0; fi < 4; ++fi)
#pragma unroll
      for (int r = 0; r < 4; ++r)
        cbuf[wv][fi * 16 + lk * 4 + r] = pp[fi][r];
  }
  __syncthreads();
  {
    const size_t slotbase = (size_t)(jb * 2 + wj) * N + i0 + wi * 64;
    ppos[slotbase + lane] = cbuf[wv][lane];
  }
}

// Kernel C1: per-row totals over 128 slots -> (pos_avg - nd), block-sum in double.
__global__ __launch_bounds__(256) void reduce1(
    const float* __restrict__ ppos, const float* __restrict__ cnt,
    const float* __restrict__ nd, double* __restrict__ bsum) {
  const int t = threadIdx.x;
  const int row = blockIdx.x * 256 + t;
  float ps = 0.f;
  for (int s = 0; s < 128; ++s)
    ps += __builtin_nontemporal_load(ppos + (size_t)s * N + row);
  float cs = fmaxf(cnt[row], 1.0f);
  double v = (double)(ps / cs) - (double)nd[row];
  __shared__ double sd[256];
  sd[t] = v;
  __syncthreads();
  for (int s2 = 128; s2 > 0; s2 >>= 1) {
    if (t < s2) sd[t] += sd[t + s2];
    __syncthreads();
  }
  if (t == 0) bsum[blockIdx.x] = sd[0];
}

// Kernel C2: sum 32 block partials, divide by N.
__global__ void reduce2(const double* __restrict__ bsum, float* __restrict__ out) {
  int lane = threadIdx.x;
  double v = (lane < 32) ? bsum[lane] : 0.0;
#pragma unroll
  for (int off = 32; off; off >>= 1) v += __shfl_down(v, off);
  if (lane == 0) out[0] = (float)(v / (double)N);
}

extern "C" void kernel_launch(void* const* d_in, const int* in_sizes, int n_in,
                              void* d_out, int out_size, void* d_ws, size_t ws_size,
                              hipStream_t stream) {
  const float* pred = (const float*)d_in[0];
  const float* mask = (const float*)d_in[1];
  const float* neg  = (const float*)d_in[2];
  float* out = (float*)d_out;

  char* ws = (char*)d_ws;
  unsigned short* phi = (unsigned short*)ws;  ws += (size_t)N * D * 2;   // 2 MB
  unsigned short* plo = (unsigned short*)ws;  ws += (size_t)N * D * 2;   // 2 MB
  float* sq  = (float*)ws;                    ws += (size_t)N * 4;
  float* nd  = (float*)ws;                    ws += (size_t)N * 4;
  float* cnt = (float*)ws;                    ws += (size_t)N * 4;
  float* ppos = (float*)ws;                   ws += (size_t)128 * N * 4; // 4 MB
  unsigned long long* bp = (unsigned long long*)ws;
  ws += (size_t)32 * N * 4 * 8;                                          // 8 MB
  double* bsum = (double*)ws;                 ws += 32 * 8;

  pack_kernel<<<N / 4, 256, 0, stream>>>(mask, bp, cnt);
  norm_kernel<<<N / 4, 256, 0, stream>>>(pred, neg, phi, plo, sq, nd);
  pair_kernel<<<(N / 128) * (N / 128), 256, 0, stream>>>(phi, plo, sq, bp, ppos);
  reduce1<<<N / 256, 256, 0, stream>>>(ppos, cnt, nd, bsum);
  reduce2<<<1, 64, 0, stream>>>(bsum, out);
}

// Round 14
// 436.665 us; speedup vs baseline: 1.0056x; 1.0056x over previous
//
#include <hip/hip_runtime.h>

#define N 8192
#define D 128

typedef __attribute__((ext_vector_type(8))) short bf16x8;
typedef __attribute__((ext_vector_type(4))) float f32x4;

__device__ __forceinline__ unsigned short f32_to_bf16_rne(float f) {
  unsigned int u = __float_as_uint(f);
  unsigned int r = (u + 0x7FFFu + ((u >> 16) & 1u)) >> 16;
  return (unsigned short)r;
}
__device__ __forceinline__ float bf16_to_f32(unsigned short h) {
  return __uint_as_float(((unsigned int)h) << 16);
}
__device__ __forceinline__ float fast_sqrt(float x) {
  float r;
  asm("v_sqrt_f32 %0, %1" : "=v"(r) : "v"(x));
  return r;
}
__device__ __forceinline__ void load_lds16(const void* g, void* l) {
  __builtin_amdgcn_global_load_lds((const __attribute__((address_space(1))) void*)g,
                                   (__attribute__((address_space(3))) void*)l,
                                   16, 0, 0);
}

// Kernel P: pack mask to bitplanes + per-row counts. One wave per row.
__global__ __launch_bounds__(256) void pack_kernel(
    const float* __restrict__ mask, unsigned long long* __restrict__ bp,
    float* __restrict__ cnt) {
  const int wv = threadIdx.x >> 6, lane = threadIdx.x & 63;
  const int row = blockIdx.x * 4 + wv;
  const f32x4* mrow = (const f32x4*)(mask + (size_t)row * N);
  int c = 0;
#pragma unroll 4
  for (int i = 0; i < 32; ++i) {
    f32x4 v = __builtin_nontemporal_load(&mrow[i * 64 + lane]);
    unsigned long long b0 = __ballot(v.x != 0.0f);
    unsigned long long b1 = __ballot(v.y != 0.0f);
    unsigned long long b2 = __ballot(v.z != 0.0f);
    unsigned long long b3 = __ballot(v.w != 0.0f);
    c += (v.x != 0.0f) + (v.y != 0.0f) + (v.z != 0.0f) + (v.w != 0.0f);
    if (lane == 0) {
      unsigned long long* d = bp + ((size_t)i * N + row) * 4;
      d[0] = b0; d[1] = b1; d[2] = b2; d[3] = b3;
    }
  }
#pragma unroll
  for (int off = 32; off; off >>= 1) c += __shfl_xor(c, off);
  if (lane == 0) cnt[row] = (float)c;
}

// Kernel A: L2-normalize pred/neg; emit phi/plo (bf16 hi/lo split), sq, nd.
__global__ __launch_bounds__(256) void norm_kernel(
    const float* __restrict__ pred, const float* __restrict__ neg,
    unsigned short* __restrict__ phi, unsigned short* __restrict__ plo,
    float* __restrict__ sq, float* __restrict__ nd) {
  int wv = threadIdx.x >> 6;
  int lane = threadIdx.x & 63;
  int row = blockIdx.x * 4 + wv;
  float2 x = ((const float2*)(pred + (size_t)row * D))[lane];
  float2 y = ((const float2*)(neg + (size_t)row * D))[lane];
  float sx = x.x * x.x + x.y * x.y;
  float sy = y.x * y.x + y.y * y.y;
#pragma unroll
  for (int off = 32; off; off >>= 1) {
    sx += __shfl_xor(sx, off);
    sy += __shfl_xor(sy, off);
  }
  float invx = 1.0f / fmaxf(sqrtf(sx), 1e-12f);
  float invy = 1.0f / fmaxf(sqrtf(sy), 1e-12f);
  float2 px = make_float2(x.x * invx, x.y * invx);
  float2 pn = make_float2(y.x * invy, y.y * invy);

  unsigned short h0 = f32_to_bf16_rne(px.x), h1 = f32_to_bf16_rne(px.y);
  unsigned short l0 = f32_to_bf16_rne(px.x - bf16_to_f32(h0));
  unsigned short l1 = f32_to_bf16_rne(px.y - bf16_to_f32(h1));
  ushort2 hv; hv.x = h0; hv.y = h1;
  ushort2 lv; lv.x = l0; lv.y = l1;
  ((ushort2*)(phi + (size_t)row * D))[lane] = hv;
  ((ushort2*)(plo + (size_t)row * D))[lane] = lv;

  float sp = px.x * px.x + px.y * px.y;
  float dx = px.x - pn.x, dy = px.y - pn.y;
  float sd = dx * dx + dy * dy;
#pragma unroll
  for (int off = 32; off; off >>= 1) {
    sp += __shfl_xor(sp, off);
    sd += __shfl_xor(sd, off);
  }
  if (lane == 0) {
    sq[row] = sp;
    nd[row] = sd > 0.0f ? sqrtf(sd) : 0.0f;
  }
}

// Kernel B: 128x128 tile; single-buffered LDS staging (global_load_lds w16,
// [128][32] bf16 chunks, conflict-free b128 frag reads), 4 waves 2x2,
// mfma 16x16x32 bf16 hi/lo 3-way split, bitmask epilogue, v_sqrt.
// bw/sqj/sqi epilogue loads hoisted above the k-loop (latency under MFMA).
__global__ __launch_bounds__(256, 3) void pair_kernel(
    const unsigned short* __restrict__ phi, const unsigned short* __restrict__ plo,
    const float* __restrict__ sq, const unsigned long long* __restrict__ bp,
    float* __restrict__ ppos) {
  __shared__ __align__(16) unsigned short aHi[128 * 32], aLo[128 * 32];
  __shared__ __align__(16) unsigned short bHi[128 * 32], bLo[128 * 32];
  __shared__ float cbuf[4][64];

  const int bid = blockIdx.x;
  // 2D XCD partition: XCD (bid&7) owns a 16x32 (ib,jb) region (bijective).
  const int xcd = bid & 7, idx = bid >> 3;
  const int ib = (xcd >> 1) * 16 + (idx & 15);
  const int jb = (xcd & 1) * 32 + (idx >> 4);
  const int i0 = ib * 128, j0 = jb * 128;

  const int t = threadIdx.x;
  const int wv = t >> 6, lane = t & 63;
  const int wi = wv >> 1, wj = wv & 1;
  const int lr = lane & 15, lk = lane >> 4;

  const int srow = t >> 2;   // staging row within 64-row pass
  const int sch = t & 3;     // 16B chunk within the 64B k-slice

  // hoisted epilogue loads: bit-words + sq values (consumed after k-loop)
  unsigned long long bw[4][4];
  const unsigned long long* bbase = bp + (size_t)(jb >> 1) * N * 4 + (lr & 3);
#pragma unroll
  for (int fi = 0; fi < 4; ++fi)
#pragma unroll
    for (int r = 0; r < 4; ++r)
      bw[fi][r] = bbase[(size_t)(i0 + wi * 64 + fi * 16 + lk * 4 + r) * 4];
  const int brow = j0 + wj * 64 + lr;
  float sqj[4];
#pragma unroll
  for (int fj = 0; fj < 4; ++fj) sqj[fj] = sq[brow + fj * 16];
  float sqi[4][4];
#pragma unroll
  for (int fi = 0; fi < 4; ++fi)
#pragma unroll
    for (int r = 0; r < 4; ++r) sqi[fi][r] = sq[i0 + wi * 64 + fi * 16 + lk * 4 + r];

  f32x4 acc[4][4];
#pragma unroll
  for (int a = 0; a < 4; ++a)
#pragma unroll
    for (int b = 0; b < 4; ++b) acc[a][b] = (f32x4){0.f, 0.f, 0.f, 0.f};

#pragma unroll 1
  for (int kc = 0; kc < 4; ++kc) {
    if (kc) __syncthreads();   // previous chunk fully consumed
#pragma unroll
    for (int pass = 0; pass < 2; ++pass) {
      const int row = pass * 64 + srow;
      const size_t ga = (size_t)(i0 + row) * D + kc * 32 + sch * 8;
      const size_t gb = (size_t)(j0 + row) * D + kc * 32 + sch * 8;
      const int loff = row * 32 + sch * 8;
      load_lds16(phi + ga, aHi + loff);
      load_lds16(plo + ga, aLo + loff);
      load_lds16(phi + gb, bHi + loff);
      load_lds16(plo + gb, bLo + loff);
    }
    __syncthreads();           // drains vmcnt; chunk visible

    bf16x8 ah[4], al[4], bh[4], bl[4];
#pragma unroll
    for (int f = 0; f < 4; ++f) {
      const int ar = (wi * 64 + f * 16 + lr) * 32 + lk * 8;
      const int br = (wj * 64 + f * 16 + lr) * 32 + lk * 8;
      ah[f] = *(const bf16x8*)(aHi + ar);
      al[f] = *(const bf16x8*)(aLo + ar);
      bh[f] = *(const bf16x8*)(bHi + br);
      bl[f] = *(const bf16x8*)(bLo + br);
    }
#pragma unroll
    for (int fi = 0; fi < 4; ++fi)
#pragma unroll
      for (int fj = 0; fj < 4; ++fj) {
        acc[fi][fj] = __builtin_amdgcn_mfma_f32_16x16x32_bf16(ah[fi], bh[fj], acc[fi][fj], 0, 0, 0);
        acc[fi][fj] = __builtin_amdgcn_mfma_f32_16x16x32_bf16(ah[fi], bl[fj], acc[fi][fj], 0, 0, 0);
        acc[fi][fj] = __builtin_amdgcn_mfma_f32_16x16x32_bf16(al[fi], bh[fj], acc[fi][fj], 0, 0, 0);
      }
  }

  // col = jb*128 + wj*64 + fj*16 + lr -> (col>>2)&63 = (jb&1)*32+wj*16+fj*4+(lr>>2)
  const int sh0 = (jb & 1) * 32 + wj * 16 + (lr >> 2);

  float pp[4][4];
#pragma unroll
  for (int a = 0; a < 4; ++a)
#pragma unroll
    for (int r = 0; r < 4; ++r) pp[a][r] = 0.f;

#pragma unroll
  for (int fi = 0; fi < 4; ++fi) {
#pragma unroll
    for (int r = 0; r < 4; ++r) {
      const unsigned long long w = bw[fi][r];
#pragma unroll
      for (int fj = 0; fj < 4; ++fj) {
        float d2 = sqi[fi][r] + sqj[fj] - 2.0f * acc[fi][fj][r];
        float dist = fast_sqrt(fmaxf(d2, 0.0f));
        pp[fi][r] += ((w >> (sh0 + fj * 4)) & 1ULL) ? dist : 0.0f;
      }
    }
  }

#pragma unroll
  for (int fi = 0; fi < 4; ++fi)
#pragma unroll
    for (int r = 0; r < 4; ++r) {
#pragma unroll
      for (int off = 1; off < 16; off <<= 1)
        pp[fi][r] += __shfl_xor(pp[fi][r], off);
    }
  if (lr == 0) {
#pragma unroll
    for (int fi = 0; fi < 4; ++fi)
#pragma unroll
      for (int r = 0; r < 4; ++r)
        cbuf[wv][fi * 16 + lk * 4 + r] = pp[fi][r];
  }
  __syncthreads();
  {
    const size_t slotbase = (size_t)(jb * 2 + wj) * N + i0 + wi * 64;
    ppos[slotbase + lane] = cbuf[wv][lane];
  }
}

// Kernel C1: per-row totals over 128 slots -> (pos_avg - nd), block-sum in double.
__global__ __launch_bounds__(256) void reduce1(
    const float* __restrict__ ppos, const float* __restrict__ cnt,
    const float* __restrict__ nd, double* __restrict__ bsum) {
  const int t = threadIdx.x;
  const int row = blockIdx.x * 256 + t;
  float ps = 0.f;
  for (int s = 0; s < 128; ++s)
    ps += __builtin_nontemporal_load(ppos + (size_t)s * N + row);
  float cs = fmaxf(cnt[row], 1.0f);
  double v = (double)(ps / cs) - (double)nd[row];
  __shared__ double sd[256];
  sd[t] = v;
  __syncthreads();
  for (int s2 = 128; s2 > 0; s2 >>= 1) {
    if (t < s2) sd[t] += sd[t + s2];
    __syncthreads();
  }
  if (t == 0) bsum[blockIdx.x] = sd[0];
}

// Kernel C2: sum 32 block partials, divide by N.
__global__ void reduce2(const double* __restrict__ bsum, float* __restrict__ out) {
  int lane = threadIdx.x;
  double v = (lane < 32) ? bsum[lane] : 0.0;
#pragma unroll
  for (int off = 32; off; off >>= 1) v += __shfl_down(v, off);
  if (lane == 0) out[0] = (float)(v / (double)N);
}

extern "C" void kernel_launch(void* const* d_in, const int* in_sizes, int n_in,
                              void* d_out, int out_size, void* d_ws, size_t ws_size,
                              hipStream_t stream) {
  const float* pred = (const float*)d_in[0];
  const float* mask = (const float*)d_in[1];
  const float* neg  = (const float*)d_in[2];
  float* out = (float*)d_out;

  char* ws = (char*)d_ws;
  unsigned short* phi = (unsigned short*)ws;  ws += (size_t)N * D * 2;   // 2 MB
  unsigned short* plo = (unsigned short*)ws;  ws += (size_t)N * D * 2;   // 2 MB
  float* sq  = (float*)ws;                    ws += (size_t)N * 4;
  float* nd  = (float*)ws;                    ws += (size_t)N * 4;
  float* cnt = (float*)ws;                    ws += (size_t)N * 4;
  float* ppos = (float*)ws;                   ws += (size_t)128 * N * 4; // 4 MB
  unsigned long long* bp = (unsigned long long*)ws;
  ws += (size_t)32 * N * 4 * 8;                                          // 8 MB
  double* bsum = (double*)ws;                 ws += 32 * 8;

  pack_kernel<<<N / 4, 256, 0, stream>>>(mask, bp, cnt);
  norm_kernel<<<N / 4, 256, 0, stream>>>(pred, neg, phi, plo, sq, nd);
  pair_kernel<<<(N / 128) * (N / 128), 256, 0, stream>>>(phi, plo, sq, bp, ppos);
  reduce1<<<N / 256, 256, 0, stream>>>(ppos, cnt, nd, bsum);
  reduce2<<<1, 64, 0, stream>>>(bsum, out);
}

// Round 16
// 417.314 us; speedup vs baseline: 1.0522x; 1.0464x over previous
//
#include <hip/hip_runtime.h>

#define N 8192
#define D 128

typedef __attribute__((ext_vector_type(8))) short bf16x8;
typedef __attribute__((ext_vector_type(4))) float f32x4;

__device__ __forceinline__ unsigned short f32_to_bf16_rne(float f) {
  unsigned int u = __float_as_uint(f);
  unsigned int r = (u + 0x7FFFu + ((u >> 16) & 1u)) >> 16;
  return (unsigned short)r;
}
__device__ __forceinline__ float bf16_to_f32(unsigned short h) {
  return __uint_as_float(((unsigned int)h) << 16);
}
__device__ __forceinline__ float fast_sqrt(float x) {
  float r;
  asm("v_sqrt_f32 %0, %1" : "=v"(r) : "v"(x));
  return r;
}
__device__ __forceinline__ void load_lds16(const void* g, void* l) {
  __builtin_amdgcn_global_load_lds((const __attribute__((address_space(1))) void*)g,
                                   (__attribute__((address_space(3))) void*)l,
                                   16, 0, 0);
}

// Kernel P: pack mask to bitplanes + per-row counts. One wave per row.
// col -> word col>>8, plane col&3, bit (col>>2)&63. Layout bp[word][row][plane].
__global__ __launch_bounds__(256) void pack_kernel(
    const float* __restrict__ mask, unsigned long long* __restrict__ bp,
    float* __restrict__ cnt) {
  const int wv = threadIdx.x >> 6, lane = threadIdx.x & 63;
  const int row = blockIdx.x * 4 + wv;
  const f32x4* mrow = (const f32x4*)(mask + (size_t)row * N);
  int c = 0;
#pragma unroll 4
  for (int i = 0; i < 32; ++i) {
    f32x4 v = __builtin_nontemporal_load(&mrow[i * 64 + lane]);
    unsigned long long b0 = __ballot(v.x != 0.0f);
    unsigned long long b1 = __ballot(v.y != 0.0f);
    unsigned long long b2 = __ballot(v.z != 0.0f);
    unsigned long long b3 = __ballot(v.w != 0.0f);
    c += (v.x != 0.0f) + (v.y != 0.0f) + (v.z != 0.0f) + (v.w != 0.0f);
    if (lane == 0) {
      unsigned long long* d = bp + ((size_t)i * N + row) * 4;
      d[0] = b0; d[1] = b1; d[2] = b2; d[3] = b3;
    }
  }
#pragma unroll
  for (int off = 32; off; off >>= 1) c += __shfl_xor(c, off);
  if (lane == 0) cnt[row] = (float)c;
}

// Kernel A: L2-normalize pred/neg; emit phi/plo (bf16 hi/lo split), sq, nd.
__global__ __launch_bounds__(256) void norm_kernel(
    const float* __restrict__ pred, const float* __restrict__ neg,
    unsigned short* __restrict__ phi, unsigned short* __restrict__ plo,
    float* __restrict__ sq, float* __restrict__ nd) {
  int wv = threadIdx.x >> 6;
  int lane = threadIdx.x & 63;
  int row = blockIdx.x * 4 + wv;
  float2 x = ((const float2*)(pred + (size_t)row * D))[lane];
  float2 y = ((const float2*)(neg + (size_t)row * D))[lane];
  float sx = x.x * x.x + x.y * x.y;
  float sy = y.x * y.x + y.y * y.y;
#pragma unroll
  for (int off = 32; off; off >>= 1) {
    sx += __shfl_xor(sx, off);
    sy += __shfl_xor(sy, off);
  }
  float invx = 1.0f / fmaxf(sqrtf(sx), 1e-12f);
  float invy = 1.0f / fmaxf(sqrtf(sy), 1e-12f);
  float2 px = make_float2(x.x * invx, x.y * invx);
  float2 pn = make_float2(y.x * invy, y.y * invy);

  unsigned short h0 = f32_to_bf16_rne(px.x), h1 = f32_to_bf16_rne(px.y);
  unsigned short l0 = f32_to_bf16_rne(px.x - bf16_to_f32(h0));
  unsigned short l1 = f32_to_bf16_rne(px.y - bf16_to_f32(h1));
  ushort2 hv; hv.x = h0; hv.y = h1;
  ushort2 lv; lv.x = l0; lv.y = l1;
  ((ushort2*)(phi + (size_t)row * D))[lane] = hv;
  ((ushort2*)(plo + (size_t)row * D))[lane] = lv;

  float sp = px.x * px.x + px.y * px.y;
  float dx = px.x - pn.x, dy = px.y - pn.y;
  float sd = dx * dx + dy * dy;
#pragma unroll
  for (int off = 32; off; off >>= 1) {
    sp += __shfl_xor(sp, off);
    sd += __shfl_xor(sd, off);
  }
  if (lane == 0) {
    sq[row] = sp;
    nd[row] = sd > 0.0f ? sqrtf(sd) : 0.0f;
  }
}

// Kernel B: SYMMETRIC pair kernel — only ib<=jb tiles (2080 blocks).
// Off-diag tiles apply dist twice: mask[i][j] bits -> slot jb*2+wj (rows i),
// mask[j][i] bits -> slot ib*2+wi (rows j). Bit-words compacted to nibble
// masks at load (8 u32 live). Single-buffered LDS staging, mfma hi/lo 3-way.
__global__ __launch_bounds__(256, 3) void pair_kernel(
    const unsigned short* __restrict__ phi, const unsigned short* __restrict__ plo,
    const float* __restrict__ sq, const unsigned long long* __restrict__ bp,
    float* __restrict__ ppos) {
  __shared__ __align__(16) unsigned short aHi[128 * 32], aLo[128 * 32];
  __shared__ __align__(16) unsigned short bHi[128 * 32], bLo[128 * 32];
  __shared__ float cbufN[4][64];
  __shared__ float cbufT[4][64];

  // XCD swizzle (2080 = 8*260, bijective) then triangular unrank ib<=jb.
  const int wgid = (blockIdx.x & 7) * 260 + (blockIdx.x >> 3);
  int ib = 0, rem = wgid, len = 64;
  while (rem >= len) { rem -= len; --len; ++ib; }
  const int jb = ib + rem;
  const int i0 = ib * 128, j0 = jb * 128;
  const bool diag = (ib == jb);

  const int t = threadIdx.x;
  const int wv = t >> 6, lane = t & 63;
  const int wi = wv >> 1, wj = wv & 1;
  const int lr = lane & 15, lk = lane >> 4;

  const int srow = t >> 2;   // staging row within 64-row pass
  const int sch = t & 3;     // 16B chunk within the 64B k-slice

  // ---- hoisted epilogue loads, compacted to nibble masks ----
  // normal: row i = i0+wi*64+fi*16+lk*4+r, col j = j0+wj*64+fj*16+lr
  const int sh0 = (jb & 1) * 32 + wj * 16 + (lr >> 2);
  const unsigned long long* bbN = bp + (size_t)(jb >> 1) * N * 4 + (lr & 3);
  unsigned nibN[4];   // [fi], bit (fj*4+r)
#pragma unroll
  for (int fi = 0; fi < 4; ++fi) {
    nibN[fi] = 0;
#pragma unroll
    for (int r = 0; r < 4; ++r) {
      unsigned long long w = bbN[(size_t)(i0 + wi * 64 + fi * 16 + lk * 4 + r) * 4];
      nibN[fi] |= ((unsigned)(w >> sh0) & 0x1111u) << r;
    }
  }
  // transposed: row j (= col above), col i -> word ib>>1, plane r, bit shT+fi*4
  const int shT = (ib & 1) * 32 + wi * 16 + lk;
  unsigned nibT[4];   // [fj], bit (fi*4+r)
  if (!diag) {
    const unsigned long long* bbT = bp + (size_t)(ib >> 1) * N * 4;
#pragma unroll
    for (int fj = 0; fj < 4; ++fj) {
      nibT[fj] = 0;
      const size_t jrow4 = (size_t)(j0 + wj * 64 + fj * 16 + lr) * 4;
#pragma unroll
      for (int r = 0; r < 4; ++r) {
        unsigned long long w = bbT[jrow4 + r];
        nibT[fj] |= ((unsigned)(w >> shT) & 0x1111u) << r;
      }
    }
  }
  const int brow = j0 + wj * 64 + lr;
  float sqj[4];
#pragma unroll
  for (int fj = 0; fj < 4; ++fj) sqj[fj] = sq[brow + fj * 16];
  float sqi[4][4];
#pragma unroll
  for (int fi = 0; fi < 4; ++fi)
#pragma unroll
    for (int r = 0; r < 4; ++r) sqi[fi][r] = sq[i0 + wi * 64 + fi * 16 + lk * 4 + r];

  f32x4 acc[4][4];
#pragma unroll
  for (int a = 0; a < 4; ++a)
#pragma unroll
    for (int b = 0; b < 4; ++b) acc[a][b] = (f32x4){0.f, 0.f, 0.f, 0.f};

#pragma unroll 1
  for (int kc = 0; kc < 4; ++kc) {
    if (kc) __syncthreads();   // previous chunk fully consumed
#pragma unroll
    for (int pass = 0; pass < 2; ++pass) {
      const int row = pass * 64 + srow;
      const size_t ga = (size_t)(i0 + row) * D + kc * 32 + sch * 8;
      const size_t gb = (size_t)(j0 + row) * D + kc * 32 + sch * 8;
      const int loff = row * 32 + sch * 8;
      load_lds16(phi + ga, aHi + loff);
      load_lds16(plo + ga, aLo + loff);
      load_lds16(phi + gb, bHi + loff);
      load_lds16(plo + gb, bLo + loff);
    }
    __syncthreads();           // drains vmcnt; chunk visible

    bf16x8 ah[4], al[4], bh[4], bl[4];
#pragma unroll
    for (int f = 0; f < 4; ++f) {
      const int ar = (wi * 64 + f * 16 + lr) * 32 + lk * 8;
      const int br = (wj * 64 + f * 16 + lr) * 32 + lk * 8;
      ah[f] = *(const bf16x8*)(aHi + ar);
      al[f] = *(const bf16x8*)(aLo + ar);
      bh[f] = *(const bf16x8*)(bHi + br);
      bl[f] = *(const bf16x8*)(bLo + br);
    }
#pragma unroll
    for (int fi = 0; fi < 4; ++fi)
#pragma unroll
      for (int fj = 0; fj < 4; ++fj) {
        acc[fi][fj] = __builtin_amdgcn_mfma_f32_16x16x32_bf16(ah[fi], bh[fj], acc[fi][fj], 0, 0, 0);
        acc[fi][fj] = __builtin_amdgcn_mfma_f32_16x16x32_bf16(ah[fi], bl[fj], acc[fi][fj], 0, 0, 0);
        acc[fi][fj] = __builtin_amdgcn_mfma_f32_16x16x32_bf16(al[fi], bh[fj], acc[fi][fj], 0, 0, 0);
      }
  }

  float pp[4][4];     // normal: per (fi,r) row partials
  float ppT[4];       // transposed: per fj column partials
#pragma unroll
  for (int a = 0; a < 4; ++a) {
    ppT[a] = 0.f;
#pragma unroll
    for (int r = 0; r < 4; ++r) pp[a][r] = 0.f;
  }

#pragma unroll
  for (int fi = 0; fi < 4; ++fi) {
#pragma unroll
    for (int r = 0; r < 4; ++r) {
#pragma unroll
      for (int fj = 0; fj < 4; ++fj) {
        float d2 = sqi[fi][r] + sqj[fj] - 2.0f * acc[fi][fj][r];
        float dist = fast_sqrt(fmaxf(d2, 0.0f));
        pp[fi][r] += ((nibN[fi] >> (fj * 4 + r)) & 1u) ? dist : 0.0f;
        if (!diag)
          ppT[fj] += ((nibT[fj] >> (fi * 4 + r)) & 1u) ? dist : 0.0f;
      }
    }
  }

  // normal reduce: over lr (16 lanes sharing each row)
#pragma unroll
  for (int fi = 0; fi < 4; ++fi)
#pragma unroll
    for (int r = 0; r < 4; ++r) {
#pragma unroll
      for (int off = 1; off < 16; off <<= 1)
        pp[fi][r] += __shfl_xor(pp[fi][r], off);
    }
  if (lr == 0) {
#pragma unroll
    for (int fi = 0; fi < 4; ++fi)
#pragma unroll
      for (int r = 0; r < 4; ++r)
        cbufN[wv][fi * 16 + lk * 4 + r] = pp[fi][r];
  }
  // transposed reduce: over lk (4 lanes sharing each column)
  if (!diag) {
#pragma unroll
    for (int fj = 0; fj < 4; ++fj) {
      ppT[fj] += __shfl_xor(ppT[fj], 16);
      ppT[fj] += __shfl_xor(ppT[fj], 32);
    }
    if (lk == 0) {
#pragma unroll
      for (int fj = 0; fj < 4; ++fj)
        cbufT[wv][fj * 16 + lr] = ppT[fj];
    }
  }
  __syncthreads();
  // coalesced slot writes (64 contiguous rows per wave)
  ppos[(size_t)(jb * 2 + wj) * N + i0 + wi * 64 + lane] = cbufN[wv][lane];
  if (!diag)
    ppos[(size_t)(ib * 2 + wi) * N + j0 + wj * 64 + lane] = cbufT[wv][lane];
}

// Kernel C1: per-row totals over 128 slots -> (pos_avg - nd), block-sum in double.
__global__ __launch_bounds__(256) void reduce1(
    const float* __restrict__ ppos, const float* __restrict__ cnt,
    const float* __restrict__ nd, double* __restrict__ bsum) {
  const int t = threadIdx.x;
  const int row = blockIdx.x * 256 + t;
  float ps = 0.f;
  for (int s = 0; s < 128; ++s)
    ps += __builtin_nontemporal_load(ppos + (size_t)s * N + row);
  float cs = fmaxf(cnt[row], 1.0f);
  double v = (double)(ps / cs) - (double)nd[row];
  __shared__ double sd[256];
  sd[t] = v;
  __syncthreads();
  for (int s2 = 128; s2 > 0; s2 >>= 1) {
    if (t < s2) sd[t] += sd[t + s2];
    __syncthreads();
  }
  if (t == 0) bsum[blockIdx.x] = sd[0];
}

// Kernel C2: sum 32 block partials, divide by N.
__global__ void reduce2(const double* __restrict__ bsum, float* __restrict__ out) {
  int lane = threadIdx.x;
  double v = (lane < 32) ? bsum[lane] : 0.0;
#pragma unroll
  for (int off = 32; off; off >>= 1) v += __shfl_down(v, off);
  if (lane == 0) out[0] = (float)(v / (double)N);
}

extern "C" void kernel_launch(void* const* d_in, const int* in_sizes, int n_in,
                              void* d_out, int out_size, void* d_ws, size_t ws_size,
                              hipStream_t stream) {
  const float* pred = (const float*)d_in[0];
  const float* mask = (const float*)d_in[1];
  const float* neg  = (const float*)d_in[2];
  float* out = (float*)d_out;

  char* ws = (char*)d_ws;
  unsigned short* phi = (unsigned short*)ws;  ws += (size_t)N * D * 2;   // 2 MB
  unsigned short* plo = (unsigned short*)ws;  ws += (size_t)N * D * 2;   // 2 MB
  float* sq  = (float*)ws;                    ws += (size_t)N * 4;
  float* nd  = (float*)ws;                    ws += (size_t)N * 4;
  float* cnt = (float*)ws;                    ws += (size_t)N * 4;
  float* ppos = (float*)ws;                   ws += (size_t)128 * N * 4; // 4 MB
  unsigned long long* bp = (unsigned long long*)ws;
  ws += (size_t)32 * N * 4 * 8;                                          // 8 MB
  double* bsum = (double*)ws;                 ws += 32 * 8;

  pack_kernel<<<N / 4, 256, 0, stream>>>(mask, bp, cnt);
  norm_kernel<<<N / 4, 256, 0, stream>>>(pred, neg, phi, plo, sq, nd);
  pair_kernel<<<2080, 256, 0, stream>>>(phi, plo, sq, bp, ppos);
  reduce1<<<N / 256, 256, 0, stream>>>(ppos, cnt, nd, bsum);
  reduce2<<<1, 64, 0, stream>>>(bsum, out);
}